// Round 17
// baseline (111.663 us; speedup 1.0000x reference)
//
#include <hip/hip_runtime.h>
#include <hip/hip_bf16.h>

typedef __attribute__((ext_vector_type(8))) short bf16x8;
typedef __attribute__((ext_vector_type(4))) float f32x4;
typedef __attribute__((ext_vector_type(4))) unsigned short u16x4;
typedef unsigned short u16;
typedef unsigned int u32;

#define DEVINL __device__ __forceinline__

DEVINL u16 f2bf(float f) {
    union { float f; u32 u; } v; v.f = f;
    u32 r = v.u + 0x7FFFu + ((v.u >> 16) & 1u);
    return (u16)(r >> 16);
}
DEVINL float bf2f(u16 h) {
    union { u32 u; float f; } v; v.u = ((u32)h) << 16;
    return v.f;
}
DEVINL u32 cvt_pk_bf16(float lo, float hi) {
    u32 r;
    asm("v_cvt_pk_bf16_f32 %0, %1, %2" : "=v"(r) : "v"(lo), "v"(hi));
    return r;
}

template<int Nv> DEVINL void vmcnt_asm() {
    if constexpr (Nv == 0) asm volatile("s_waitcnt vmcnt(0)" ::: "memory");
    else if constexpr (Nv == 2) asm volatile("s_waitcnt vmcnt(2)" ::: "memory");
    else if constexpr (Nv == 3) asm volatile("s_waitcnt vmcnt(3)" ::: "memory");
    else if constexpr (Nv == 4) asm volatile("s_waitcnt vmcnt(4)" ::: "memory");
    else if constexpr (Nv == 5) asm volatile("s_waitcnt vmcnt(5)" ::: "memory");
    else if constexpr (Nv == 6) asm volatile("s_waitcnt vmcnt(6)" ::: "memory");
    else if constexpr (Nv == 7) asm volatile("s_waitcnt vmcnt(7)" ::: "memory");
    else if constexpr (Nv == 8) asm volatile("s_waitcnt vmcnt(8)" ::: "memory");
    else if constexpr (Nv == 12) asm volatile("s_waitcnt vmcnt(12)" ::: "memory");
    else if constexpr (Nv == 14) asm volatile("s_waitcnt vmcnt(14)" ::: "memory");
    else asm volatile("s_waitcnt vmcnt(10)" ::: "memory");
}

// async global->LDS, 16B per lane; LDS dest = wave-uniform base + lane*16
#define GLOAD_LDS16(g, l) __builtin_amdgcn_global_load_lds( \
    (const __attribute__((address_space(1))) void*)(g), \
    (__attribute__((address_space(3))) void*)(l), 16, 0, 0)

#define SBAR() do { \
    __builtin_amdgcn_sched_barrier(0); \
    __builtin_amdgcn_s_barrier(); \
    __builtin_amdgcn_sched_barrier(0); } while (0)

// ---------------- fused prep: x->bf16 cvt + both weight transposes ----------------
__global__ __launch_bounds__(256) void prep_kernel(const float* __restrict__ x,
                                                   u16* __restrict__ xb,
                                                   const float* __restrict__ W_qkv,
                                                   u16* __restrict__ Wqkv_t,
                                                   const float* __restrict__ W_out,
                                                   u16* __restrict__ Wout_t) {
    __shared__ float tile[32][33];
    const int bid = blockIdx.x;
    if (bid < 3072) {
        int t = bid * 256 + threadIdx.x;
        const float4 v0 = reinterpret_cast<const float4*>(x)[t * 2];
        const float4 v1 = reinterpret_cast<const float4*>(x)[t * 2 + 1];
        u16 o[8];
        o[0] = f2bf(v0.x); o[1] = f2bf(v0.y); o[2] = f2bf(v0.z); o[3] = f2bf(v0.w);
        o[4] = f2bf(v1.x); o[5] = f2bf(v1.y); o[6] = f2bf(v1.z); o[7] = f2bf(v1.w);
        *reinterpret_cast<bf16x8*>(xb + (size_t)t * 8) = *reinterpret_cast<bf16x8*>(o);
        return;
    }
    const float* in; u16* out; int R, C, bx, by;
    if (bid < 4800) {
        int u = bid - 3072; in = W_qkv; out = Wqkv_t; R = 768; C = 2304;
        bx = u % 72; by = u / 72;
    } else {
        int u = bid - 4800; in = W_out; out = Wout_t; R = 768; C = 768;
        bx = u % 24; by = u / 24;
    }
    int c0 = bx * 32, r0 = by * 32;
    int tx = threadIdx.x & 31, ty = threadIdx.x >> 5;
#pragma unroll
    for (int i = 0; i < 4; ++i)
        tile[ty + i * 8][tx] = in[(size_t)(r0 + ty + i * 8) * C + c0 + tx];
    __syncthreads();
#pragma unroll
    for (int i = 0; i < 4; ++i)
        out[(size_t)(c0 + ty + i * 8) * R + r0 + tx] = f2bf(tile[tx][ty + i * 8]);
}

// =====================================================================
// GEMM1 v5: tile 128x288, BK=32, 4 waves (2Mx2N), wave 64x144 (mf4 x nf9).
// Grid 512 = 2 blocks/CU, 3 LDS buffers, 2-K-tile-deep counted vmcnt.
// FUSED GPT-J ROTARY in epilogue, with the block's 128 pos rows (32 KiB)
// STAGED INTO LDS first (buffers are dead after the K-loop) -> sv/cv come
// from LDS (broadcast/4-way), not 288 scalar global loads (r15's mistake).
// Pair partner (col^1) is lane lr^1 -> one shfl_xor per value. q cols
// scaled by 0.125*log2e (exp2-domain softmax downstream).
// =====================================================================
template<int K>
__global__ __launch_bounds__(256, 2) void gemm1_kernel(const u16* __restrict__ A,
                                                       const u16* __restrict__ Bt,
                                                       u16* __restrict__ Cout,
                                                       const float* __restrict__ pos) {
    constexpr int NT = K / 32;               // 24
    constexpr int PBUF = (128 + 288) * 32;   // 13312 elems per buffer
    __shared__ u16 lds[3 * PBUF];            // 78 KiB

    const int tid = threadIdx.x;
    const int wv = tid >> 6, lane = tid & 63;
    const int lr = lane & 15, lg = lane >> 4;
    const int wr = wv >> 1, wc = wv & 1;

    // XCD-aware bijective swizzle over 512 = 8 x 64
    const int id = blockIdx.x;
    const int sid = (id & 7) * 64 + (id >> 3);
    const int bm = (sid >> 3) * 128;
    const int bn = (sid & 7) * 288;

#define STAGE(nb_, kt_) do { \
    _Pragma("unroll") \
    for (int j_ = 0; j_ < 2; ++j_) { \
        const int idx_ = j_ * 256 + tid; \
        const int row_ = idx_ >> 2; \
        const int c_ = (idx_ & 3) ^ ((row_ >> 1) & 3); \
        GLOAD_LDS16(A + (size_t)(bm + row_) * K + (kt_) * 32 + c_ * 8, \
                    (char*)lds + (nb_) * (PBUF * 2) + idx_ * 16); \
    } \
    _Pragma("unroll") \
    for (int j_ = 0; j_ < 4; ++j_) { \
        const int idx_ = j_ * 256 + tid; \
        const int row_ = idx_ >> 2; \
        const int c_ = (idx_ & 3) ^ ((row_ >> 1) & 3); \
        GLOAD_LDS16(Bt + (size_t)(bn + row_) * K + (kt_) * 32 + c_ * 8, \
                    (char*)lds + (nb_) * (PBUF * 2) + 8192 + idx_ * 16); \
    } \
    if (tid < 128) { \
        const int idx_ = 1024 + tid; \
        const int row_ = idx_ >> 2; \
        const int c_ = (idx_ & 3) ^ ((row_ >> 1) & 3); \
        GLOAD_LDS16(Bt + (size_t)(bn + row_) * K + (kt_) * 32 + c_ * 8, \
                    (char*)lds + (nb_) * (PBUF * 2) + 8192 + idx_ * 16); \
    } } while (0)

    f32x4 acc[4][9];
#pragma unroll
    for (int i = 0; i < 4; ++i)
#pragma unroll
        for (int j = 0; j < 9; ++j) acc[i][j] = (f32x4){0.f, 0.f, 0.f, 0.f};

    // prologue: two stages in flight
    STAGE(0, 0);
    STAGE(1, 1);

    for (int kt = 0; kt < NT; ++kt) {
        const int cur = kt % 3;
        if (kt < NT - 2) {
            STAGE((kt + 2) % 3, kt + 2);
            __builtin_amdgcn_sched_barrier(0);
            if (wv < 2) vmcnt_asm<14>();   // kt's 7 done; kt+1,kt+2 (14) in flight
            else vmcnt_asm<12>();
        } else if (kt == NT - 2) {
            __builtin_amdgcn_sched_barrier(0);
            if (wv < 2) vmcnt_asm<7>();    // drain kt; kt+1 stays
            else vmcnt_asm<6>();
        } else {
            __builtin_amdgcn_sched_barrier(0);
            vmcnt_asm<0>();
        }
        SBAR();
        bf16x8 af[4], bfr[9];
#pragma unroll
        for (int mf = 0; mf < 4; ++mf) {
            const int row = wr * 64 + mf * 16 + lr;
            af[mf] = *reinterpret_cast<const bf16x8*>(
                &lds[cur * PBUF + row * 32 + ((lg ^ ((row >> 1) & 3)) << 3)]);
        }
#pragma unroll
        for (int nf = 0; nf < 9; ++nf) {
            const int row = wc * 144 + nf * 16 + lr;
            bfr[nf] = *reinterpret_cast<const bf16x8*>(
                &lds[cur * PBUF + 4096 + row * 32 + ((lg ^ ((row >> 1) & 3)) << 3)]);
        }
        __builtin_amdgcn_s_setprio(1);
#pragma unroll
        for (int mf = 0; mf < 4; ++mf)
#pragma unroll
            for (int nf = 0; nf < 9; ++nf)
                acc[mf][nf] = __builtin_amdgcn_mfma_f32_16x16x32_bf16(
                    af[mf], bfr[nf], acc[mf][nf], 0, 0, 0);
        __builtin_amdgcn_s_setprio(0);
        SBAR();
    }

    // ---- stage pos rows (bm..bm+127 -> n0..n0+127) into dead LDS, 32 KiB ----
    // (skip for pure-V blocks: bn >= 1536 means all cols >= 1536)
    const float* posl = (const float*)lds;
    if (bn < 1536) {
        const int n0 = bm & 1023;   // 128 | 1024 so no wrap within a block
#pragma unroll
        for (int j = 0; j < 8; ++j) {
            const int c = j * 256 + tid;     // 16B chunk = 4 floats, linear
            GLOAD_LDS16(pos + (size_t)n0 * 64 + c * 4, (char*)lds + j * 4096 + tid * 16);
        }
        __builtin_amdgcn_sched_barrier(0);
        vmcnt_asm<0>();
        SBAR();
    }

    // epilogue: C/D layout col=lane&15, row=(lane>>4)*4+r (verified);
    // fused rotary for q/k cols (16-col lane blocks never straddle 768/1536).
#pragma unroll
    for (int mf = 0; mf < 4; ++mf)
#pragma unroll
        for (int nf = 0; nf < 9; ++nf) {
            const int col = bn + wc * 144 + nf * 16 + lr;
            const int i0 = (col & 63) >> 1;
            const bool dorot = (col < 1536);
            const float qs = (col < 768) ? 0.18033688f : 1.0f;  // 0.125*log2e
#pragma unroll
            for (int r = 0; r < 4; ++r) {
                const int row = bm + wr * 64 + mf * 16 + lg * 4 + r;
                float val = acc[mf][nf][r];
                float prt = __shfl_xor(val, 1);   // pair partner (col^1)
                float outv = val;
                if (dorot) {
                    const int nn = row & 127;
                    const float sv = posl[nn * 64 + i0];
                    const float cv = posl[nn * 64 + 32 + i0];
                    outv = ((col & 1) ? (val * cv + prt * sv)
                                      : (val * cv - prt * sv)) * qs;
                }
                Cout[(size_t)row * 2304 + col] = f2bf(outv);
            }
        }
#undef STAGE
}

// =====================================================================
// Big-tile GEMM (gemm2): tile 256x96, grid exactly 256, 4-phase K-loop.
// =====================================================================
template<int NTN, int NFRAG, int BROWS, int K, bool BF16_OUT>
__global__ __launch_bounds__(512, 2) void gemm_bigtile_kernel(const u16* __restrict__ A,
                                                              const u16* __restrict__ Bt,
                                                              void* __restrict__ Cout,
                                                              const float* __restrict__ bias) {
    constexpr int BN = NFRAG * 32;
    constexpr int N = NTN * BN;
    constexpr int NT = K / 64;
    constexpr int PA = 256 * 32;
    constexpr int PB = BROWS * 32;
    constexpr int PKS = PA + PB;
    constexpr int PBUF = 2 * PKS;
    constexpr int BFULL = (BROWS * 4) / 512;
    constexpr int BREM = (BROWS * 4) % 512;
    __shared__ u16 lds[2 * PBUF];

    const int tid = threadIdx.x;
    const int wv = tid >> 6, lane = tid & 63;
    const int lr = lane & 15, lg = lane >> 4;
    const int wr = wv >> 1, wc = wv & 1;

    const int id = blockIdx.x;
    const int sid = (id & 7) * 32 + (id >> 3);
    const int bm = (sid / NTN) * 256;
    const int bn = (sid % NTN) * BN;

#define PL(buf_, ks_, mat_) ((buf_) * PBUF + (ks_) * PKS + (mat_) * PA)

#define STAGE_A(nb_, kt_, ks_) do { \
    _Pragma("unroll") \
    for (int j_ = 0; j_ < 2; ++j_) { \
        const int idx_ = j_ * 512 + tid; \
        const int row_ = idx_ >> 2; \
        const int c_ = (idx_ & 3) ^ ((row_ >> 1) & 3); \
        GLOAD_LDS16(A + (size_t)(bm + row_) * K + (kt_) * 64 + (ks_) * 32 + c_ * 8, \
                    (char*)lds + PL((nb_), (ks_), 0) * 2 + j_ * 8192 + tid * 16); \
    } } while (0)

#define STAGE_B(nb_, kt_, ks_) do { \
    _Pragma("unroll") \
    for (int j_ = 0; j_ < BFULL; ++j_) { \
        const int idx_ = j_ * 512 + tid; \
        const int row_ = idx_ >> 2; \
        const int c_ = (idx_ & 3) ^ ((row_ >> 1) & 3); \
        GLOAD_LDS16(Bt + (size_t)(bn + row_) * K + (kt_) * 64 + (ks_) * 32 + c_ * 8, \
                    (char*)lds + PL((nb_), (ks_), 1) * 2 + j_ * 8192 + tid * 16); \
    } \
    if constexpr (BREM != 0) { \
        if (tid < BREM) { \
            const int idx_ = BFULL * 512 + tid; \
            const int row_ = idx_ >> 2; \
            const int c_ = (idx_ & 3) ^ ((row_ >> 1) & 3); \
            GLOAD_LDS16(Bt + (size_t)(bn + row_) * K + (kt_) * 64 + (ks_) * 32 + c_ * 8, \
                        (char*)lds + PL((nb_), (ks_), 1) * 2 + BFULL * 8192 + tid * 16); \
        } \
    } } while (0)

#define LDA(mh_, ks_, cur_) do { \
    _Pragma("unroll") \
    for (int f_ = 0; f_ < 2; ++f_) { \
        const int row_ = wr * 64 + (mh_) * 32 + f_ * 16 + lr; \
        af[f_] = *reinterpret_cast<const bf16x8*>( \
            &lds[PL((cur_), (ks_), 0) + row_ * 32 + ((lg ^ ((row_ >> 1) & 3)) << 3)]); \
    } } while (0)

#define LDB(ks_, cur_) do { \
    _Pragma("unroll") \
    for (int nf_ = 0; nf_ < NFRAG; ++nf_) { \
        const int row_ = wc * (NFRAG * 16) + nf_ * 16 + lr; \
        bfr[nf_] = *reinterpret_cast<const bf16x8*>( \
            &lds[PL((cur_), (ks_), 1) + row_ * 32 + ((lg ^ ((row_ >> 1) & 3)) << 3)]); \
    } } while (0)

#define MFMAQ(mh_) do { \
    __builtin_amdgcn_s_setprio(1); \
    _Pragma("unroll") \
    for (int f_ = 0; f_ < 2; ++f_) \
    _Pragma("unroll") \
    for (int nf_ = 0; nf_ < NFRAG; ++nf_) \
        acc[(mh_) * 2 + f_][nf_] = __builtin_amdgcn_mfma_f32_16x16x32_bf16( \
            af[f_], bfr[nf_], acc[(mh_) * 2 + f_][nf_], 0, 0, 0); \
    __builtin_amdgcn_s_setprio(0); } while (0)

#define WAITHALF() do { \
    __builtin_amdgcn_sched_barrier(0); \
    if constexpr (BREM != 0) { \
        if (wv < BREM / 64) vmcnt_asm<2 + BFULL + 1>(); \
        else vmcnt_asm<2 + BFULL>(); \
    } else { \
        vmcnt_asm<2 + BFULL>(); \
    } } while (0)

    f32x4 acc[4][NFRAG];
#pragma unroll
    for (int i = 0; i < 4; ++i)
#pragma unroll
        for (int j = 0; j < NFRAG; ++j) acc[i][j] = (f32x4){0.f, 0.f, 0.f, 0.f};

    bf16x8 af[2], bfr[NFRAG];

    STAGE_A(0, 0, 0); STAGE_B(0, 0, 0); STAGE_A(0, 0, 1); STAGE_B(0, 0, 1);
    __builtin_amdgcn_sched_barrier(0);
    vmcnt_asm<0>();
    SBAR();

    for (int kt = 0; kt < NT - 1; ++kt) {
        const int cur = kt & 1, nxt = cur ^ 1;
        LDB(0, cur); LDA(0, 0, cur);
        STAGE_A(nxt, kt + 1, 0);
        SBAR(); MFMAQ(0); SBAR();
        LDA(1, 0, cur);
        STAGE_B(nxt, kt + 1, 0);
        WAITHALF();
        SBAR(); MFMAQ(1); SBAR();
        LDB(1, cur); LDA(0, 1, cur);
        STAGE_A(nxt, kt + 1, 1);
        SBAR(); MFMAQ(0); SBAR();
        LDA(1, 1, cur);
        STAGE_B(nxt, kt + 1, 1);
        WAITHALF();
        SBAR(); MFMAQ(1); SBAR();
    }
    {
        const int cur = (NT - 1) & 1;
        LDB(0, cur); LDA(0, 0, cur); SBAR(); MFMAQ(0); SBAR();
        LDA(1, 0, cur);
        __builtin_amdgcn_sched_barrier(0);
        vmcnt_asm<0>();
        SBAR(); MFMAQ(1); SBAR();
        LDB(1, cur); LDA(0, 1, cur); SBAR(); MFMAQ(0); SBAR();
        LDA(1, 1, cur); SBAR(); MFMAQ(1);
    }

#pragma unroll
    for (int mf = 0; mf < 4; ++mf)
#pragma unroll
        for (int nf = 0; nf < NFRAG; ++nf) {
            const int col = bn + wc * (NFRAG * 16) + nf * 16 + lr;
            const float bv = BF16_OUT ? 0.f : bias[col];
#pragma unroll
            for (int r = 0; r < 4; ++r) {
                const int row = bm + wr * 64 + mf * 16 + lg * 4 + r;
                if (BF16_OUT)
                    ((u16*)Cout)[(size_t)row * N + col] = f2bf(acc[mf][nf][r]);
                else
                    ((float*)Cout)[(size_t)row * N + col] = acc[mf][nf][r] + bv;
            }
        }
#undef PL
#undef STAGE_A
#undef STAGE_B
#undef LDA
#undef LDB
#undef MFMAQ
#undef WAITHALF
}

// ---------------- V transpose: qkv v-part [n][d] -> Vt[bh][d][n] ----------------
__global__ __launch_bounds__(256) void vtrans_kernel(const u16* __restrict__ qkv, u16* __restrict__ Vt) {
    __shared__ u16 tile[64][72];
    int nt = blockIdx.x;   // 0..15
    int bh = blockIdx.y;   // 0..95
    int b = bh / 12, h = bh % 12;
    int tid = threadIdx.x;
    int rr = tid >> 3, cc = (tid & 7) * 8;
#pragma unroll
    for (int it = 0; it < 2; ++it) {
        int nloc = it * 32 + rr;
        const u16* src = qkv + (size_t)(b * 1024 + nt * 64 + nloc) * 2304 + 1536 + h * 64 + cc;
        bf16x8 v = *reinterpret_cast<const bf16x8*>(src);
#pragma unroll
        for (int j = 0; j < 8; ++j) tile[nloc][cc + j] = (u16)v[j];
    }
    __syncthreads();
#pragma unroll
    for (int it = 0; it < 2; ++it) {
        int d = it * 32 + rr;
        u16 o[8];
#pragma unroll
        for (int j = 0; j < 8; ++j) o[j] = tile[cc + j][d];
        *reinterpret_cast<bf16x8*>(Vt + (size_t)(bh * 64 + d) * 1024 + nt * 64 + cc) =
            *reinterpret_cast<bf16x8*>(o);
    }
}

// ---------------- flash attention v7: 4 waves x 32 q, 3-buf 2-deep, raw barriers ----------------
__global__ __launch_bounds__(256, 3) void attn_kernel(const u16* __restrict__ qkv,
                                                      const u16* __restrict__ Vt,
                                                      u16* __restrict__ attn_out) {
    __shared__ u16 Ks[3][64 * 64];
    __shared__ u16 Vs[3][64 * 64];
    const int d_ = blockIdx.x;
    const int bh = ((d_ >> 3) >> 3) * 8 + (d_ & 7);  // bh%8 == blockIdx%8 == XCD
    const int qt = (d_ >> 3) & 7;
    const int b = bh / 12, h = bh % 12;
    const int tid = threadIdx.x;
    const int w = tid >> 6, lr = tid & 15, lg = (tid >> 4) & 3;

    bf16x8 qf[2][2];
#pragma unroll
    for (int q = 0; q < 2; ++q)
#pragma unroll
        for (int ds = 0; ds < 2; ++ds)
            qf[q][ds] = *reinterpret_cast<const bf16x8*>(
                &qkv[(size_t)(b * 1024 + qt * 128 + w * 32 + q * 16 + lr) * 2304 +
                     h * 64 + ds * 32 + lg * 8]);

    f32x4 o[2][4];
#pragma unroll
    for (int q = 0; q < 2; ++q)
#pragma unroll
        for (int i = 0; i < 4; ++i) o[q][i] = (f32x4){0.f, 0.f, 0.f, 0.f};
    float lsum[2] = {0.f, 0.f};

#define STAGE_KV(nb, kt_) do { \
    _Pragma("unroll") \
    for (int j_ = 0; j_ < 2; ++j_) { \
        const int idx_ = j_ * 256 + tid; \
        const int row_ = idx_ >> 3; \
        const int sc_ = ((idx_ & 7) ^ (row_ & 7)) * 8; \
        const int rk_ = (row_ & 0x20) | ((row_ & 0x0C) << 1) | ((row_ & 0x10) >> 2) | (row_ & 3); \
        GLOAD_LDS16(qkv + (size_t)(b * 1024 + (kt_) * 64 + rk_) * 2304 + 768 + h * 64 + sc_, \
                    (char*)Ks[nb] + idx_ * 16); \
        GLOAD_LDS16(Vt + (size_t)(bh * 64 + row_) * 1024 + (kt_) * 64 + sc_, \
                    (char*)Vs[nb] + idx_ * 16); \
    } } while (0)

    // prologue: two stages in flight (kt=0 into buf0, kt=1 into buf1)
    STAGE_KV(0, 0);
    STAGE_KV(1, 1);

    const int rsw = lr & 7;

    for (int kt = 0; kt < 16; ++kt) {
        const int cur = kt % 3;
        if (kt < 14) {
            STAGE_KV((kt + 2) % 3, kt + 2);
            __builtin_amdgcn_sched_barrier(0);
            vmcnt_asm<8>();   // kt's 4 loads done; kt+1,kt+2 (8) stay in flight
        } else if (kt == 14) {
            __builtin_amdgcn_sched_barrier(0);
            vmcnt_asm<4>();
        } else {
            __builtin_amdgcn_sched_barrier(0);
            vmcnt_asm<0>();
        }
        SBAR();

        f32x4 s[2][4];
        __builtin_amdgcn_s_setprio(1);
#pragma unroll
        for (int kf = 0; kf < 4; ++kf) {
            bf16x8 k0 = *reinterpret_cast<const bf16x8*>(
                &Ks[cur][(kf * 16 + lr) * 64 + ((lg ^ rsw) * 8)]);
            bf16x8 k1 = *reinterpret_cast<const bf16x8*>(
                &Ks[cur][(kf * 16 + lr) * 64 + (((4 + lg) ^ rsw) * 8)]);
#pragma unroll
            for (int q = 0; q < 2; ++q) {
                f32x4 a = __builtin_amdgcn_mfma_f32_16x16x32_bf16(
                    k0, qf[q][0], (f32x4){0.f, 0.f, 0.f, 0.f}, 0, 0, 0);
                s[q][kf] = __builtin_amdgcn_mfma_f32_16x16x32_bf16(k1, qf[q][1], a, 0, 0, 0);
            }
        }
        __builtin_amdgcn_s_setprio(0);

        union { u32 wd[4]; bf16x8 v; } pk[2][2];
#pragma unroll
        for (int q = 0; q < 2; ++q) {
#pragma unroll
            for (int kf = 0; kf < 4; ++kf)
#pragma unroll
                for (int r = 0; r < 4; ++r) s[q][kf][r] = __builtin_amdgcn_exp2f(s[q][kf][r]);
            float t0 = (s[q][0][0] + s[q][0][1]) + (s[q][0][2] + s[q][0][3]);
            float t1 = (s[q][1][0] + s[q][1][1]) + (s[q][1][2] + s[q][1][3]);
            float t2 = (s[q][2][0] + s[q][2][1]) + (s[q][2][2] + s[q][2][3]);
            float t3 = (s[q][3][0] + s[q][3][1]) + (s[q][3][2] + s[q][3][3]);
            lsum[q] += (t0 + t1) + (t2 + t3);
#pragma unroll
            for (int ks = 0; ks < 2; ++ks) {
                pk[q][ks].wd[0] = cvt_pk_bf16(s[q][2 * ks][0], s[q][2 * ks][1]);
                pk[q][ks].wd[1] = cvt_pk_bf16(s[q][2 * ks][2], s[q][2 * ks][3]);
                pk[q][ks].wd[2] = cvt_pk_bf16(s[q][2 * ks + 1][0], s[q][2 * ks + 1][1]);
                pk[q][ks].wd[3] = cvt_pk_bf16(s[q][2 * ks + 1][2], s[q][2 * ks + 1][3]);
            }
        }

        __builtin_amdgcn_s_setprio(1);
#pragma unroll
        for (int ks = 0; ks < 2; ++ks) {
#pragma unroll
            for (int df = 0; df < 4; ++df) {
                bf16x8 vb = *reinterpret_cast<const bf16x8*>(
                    &Vs[cur][(df * 16 + lr) * 64 + (((ks * 4 + lg) ^ rsw) * 8)]);
                o[0][df] = __builtin_amdgcn_mfma_f32_16x16x32_bf16(vb, pk[0][ks].v, o[0][df], 0, 0, 0);
                o[1][df] = __builtin_amdgcn_mfma_f32_16x16x32_bf16(vb, pk[1][ks].v, o[1][df], 0, 0, 0);
            }
        }
        __builtin_amdgcn_s_setprio(0);
        SBAR();
    }
#undef STAGE_KV

#pragma unroll
    for (int q = 0; q < 2; ++q) {
        float l = lsum[q];
        l += __shfl_xor(l, 16);
        l += __shfl_xor(l, 32);
        const float linv = 1.0f / l;
        u16* orow = attn_out +
            (size_t)(b * 1024 + qt * 128 + w * 32 + q * 16 + lr) * 768 + h * 64 + lg * 4;
#pragma unroll
        for (int df = 0; df < 4; ++df) {
            uint2 st;
            st.x = cvt_pk_bf16(o[q][df][0] * linv, o[q][df][1] * linv);
            st.y = cvt_pk_bf16(o[q][df][2] * linv, o[q][df][3] * linv);
            *reinterpret_cast<uint2*>(orow + df * 16) = st;
        }
    }
}

extern "C" void kernel_launch(void* const* d_in, const int* in_sizes, int n_in,
                              void* d_out, int out_size, void* d_ws, size_t ws_size,
                              hipStream_t stream) {
    (void)in_sizes; (void)n_in; (void)out_size; (void)ws_size;
    const float* x     = (const float*)d_in[0];   // [8,1024,768]
    const float* pos   = (const float*)d_in[1];   // [1,1024,64]
    const float* W_qkv = (const float*)d_in[2];   // [768,2304]
    const float* W_out = (const float*)d_in[3];   // [768,768]
    const float* b_out = (const float*)d_in[4];   // [768]
    float* out = (float*)d_out;                   // [8,1024,768]

    // workspace layout (bytes); Wqkv_t padded to 2336 rows, Wout_t to 800 rows
    char* ws = (char*)d_ws;
    u16* xb     = (u16*)(ws);                       // 8192x768   bf16 (12582912)
    u16* Wqkv_t = (u16*)(ws + 12582912);            // 2336x768   bf16 (3588096)
    u16* Wout_t = (u16*)(ws + 16171008);            // 800x768    bf16 (1228800)
    u16* qkv    = (u16*)(ws + 17399808);            // 8192x2304  bf16 (37748736)
    u16* Vt     = (u16*)(ws + 55148544);            // 96x64x1024 bf16 (12582912)
    u16* attn_o = (u16*)(ws + 67731456);            // 8192x768   bf16 (12582912)

    prep_kernel<<<5376, 256, 0, stream>>>(x, xb, W_qkv, Wqkv_t, W_out, Wout_t);
    // qkv = rot(xb @ Wqkv^T) : rotary fused into GEMM epilogue, pos via LDS
    gemm1_kernel<768><<<512, 256, 0, stream>>>(xb, Wqkv_t, qkv, pos);
    vtrans_kernel<<<dim3(16, 96), 256, 0, stream>>>(qkv, Vt);
    attn_kernel<<<768, 256, 0, stream>>>(qkv, Vt, attn_o);
    // out = attn_o @ Wout^T + b : tile 256x96, grid exactly 256
    gemm_bigtile_kernel<8, 3, 128, 768, false><<<256, 512, 0, stream>>>(attn_o, Wout_t, out, b_out);
}

// Round 18
// 109.061 us; speedup vs baseline: 1.0239x; 1.0239x over previous
//
#include <hip/hip_runtime.h>
#include <hip/hip_bf16.h>

typedef __attribute__((ext_vector_type(8))) short bf16x8;
typedef __attribute__((ext_vector_type(4))) float f32x4;
typedef __attribute__((ext_vector_type(4))) unsigned short u16x4;
typedef unsigned short u16;
typedef unsigned int u32;

#define DEVINL __device__ __forceinline__

DEVINL u16 f2bf(float f) {
    union { float f; u32 u; } v; v.f = f;
    u32 r = v.u + 0x7FFFu + ((v.u >> 16) & 1u);
    return (u16)(r >> 16);
}
DEVINL float bf2f(u16 h) {
    union { u32 u; float f; } v; v.u = ((u32)h) << 16;
    return v.f;
}
DEVINL u32 cvt_pk_bf16(float lo, float hi) {
    u32 r;
    asm("v_cvt_pk_bf16_f32 %0, %1, %2" : "=v"(r) : "v"(lo), "v"(hi));
    return r;
}

template<int Nv> DEVINL void vmcnt_asm() {
    if constexpr (Nv == 0) asm volatile("s_waitcnt vmcnt(0)" ::: "memory");
    else if constexpr (Nv == 2) asm volatile("s_waitcnt vmcnt(2)" ::: "memory");
    else if constexpr (Nv == 3) asm volatile("s_waitcnt vmcnt(3)" ::: "memory");
    else if constexpr (Nv == 4) asm volatile("s_waitcnt vmcnt(4)" ::: "memory");
    else if constexpr (Nv == 5) asm volatile("s_waitcnt vmcnt(5)" ::: "memory");
    else if constexpr (Nv == 6) asm volatile("s_waitcnt vmcnt(6)" ::: "memory");
    else if constexpr (Nv == 7) asm volatile("s_waitcnt vmcnt(7)" ::: "memory");
    else if constexpr (Nv == 8) asm volatile("s_waitcnt vmcnt(8)" ::: "memory");
    else asm volatile("s_waitcnt vmcnt(4)" ::: "memory");
}

// async global->LDS, 16B per lane; LDS dest = wave-uniform base + lane*16
#define GLOAD_LDS16(g, l) __builtin_amdgcn_global_load_lds( \
    (const __attribute__((address_space(1))) void*)(g), \
    (__attribute__((address_space(3))) void*)(l), 16, 0, 0)

#define SBAR() do { \
    __builtin_amdgcn_sched_barrier(0); \
    __builtin_amdgcn_s_barrier(); \
    __builtin_amdgcn_sched_barrier(0); } while (0)

// ---------------- fused prep: x->bf16 cvt + both weight transposes ----------------
__global__ __launch_bounds__(256) void prep_kernel(const float* __restrict__ x,
                                                   u16* __restrict__ xb,
                                                   const float* __restrict__ W_qkv,
                                                   u16* __restrict__ Wqkv_t,
                                                   const float* __restrict__ W_out,
                                                   u16* __restrict__ Wout_t) {
    __shared__ float tile[32][33];
    const int bid = blockIdx.x;
    if (bid < 3072) {
        int t = bid * 256 + threadIdx.x;
        const float4 v0 = reinterpret_cast<const float4*>(x)[t * 2];
        const float4 v1 = reinterpret_cast<const float4*>(x)[t * 2 + 1];
        u16 o[8];
        o[0] = f2bf(v0.x); o[1] = f2bf(v0.y); o[2] = f2bf(v0.z); o[3] = f2bf(v0.w);
        o[4] = f2bf(v1.x); o[5] = f2bf(v1.y); o[6] = f2bf(v1.z); o[7] = f2bf(v1.w);
        *reinterpret_cast<bf16x8*>(xb + (size_t)t * 8) = *reinterpret_cast<bf16x8*>(o);
        return;
    }
    const float* in; u16* out; int R, C, bx, by;
    if (bid < 4800) {
        int u = bid - 3072; in = W_qkv; out = Wqkv_t; R = 768; C = 2304;
        bx = u % 72; by = u / 72;
    } else {
        int u = bid - 4800; in = W_out; out = Wout_t; R = 768; C = 768;
        bx = u % 24; by = u / 24;
    }
    int c0 = bx * 32, r0 = by * 32;
    int tx = threadIdx.x & 31, ty = threadIdx.x >> 5;
#pragma unroll
    for (int i = 0; i < 4; ++i)
        tile[ty + i * 8][tx] = in[(size_t)(r0 + ty + i * 8) * C + c0 + tx];
    __syncthreads();
#pragma unroll
    for (int i = 0; i < 4; ++i)
        out[(size_t)(c0 + ty + i * 8) * R + r0 + tx] = f2bf(tile[tx][ty + i * 8]);
}

// =====================================================================
// GEMM1 (r12 config, best measured 43.0 us): tile 128x192, BK=32,
// 4 waves (2Mx2N), wave 64x96 (mf4 x nf6). Grid 768 = 3 blocks/CU,
// counted vmcnt(5); tail iteration drains vmcnt(0). Chunk swizzle
// c^=(row>>1)&3 on both sides (measured 0 conflicts).
// =====================================================================
template<int K>
__global__ __launch_bounds__(256, 3) void gemm1_kernel(const u16* __restrict__ A,
                                                       const u16* __restrict__ Bt,
                                                       u16* __restrict__ Cout) {
    constexpr int NT = K / 32;
    constexpr int PBUF = (128 + 192) * 32;   // elems per buffer (A|B planes)
    __shared__ u16 lds[2 * PBUF];

    const int tid = threadIdx.x;
    const int wv = tid >> 6, lane = tid & 63;
    const int lr = lane & 15, lg = lane >> 4;
    const int wr = wv >> 1, wc = wv & 1;

    // XCD-aware bijective swizzle over 768 = 8 x 96
    const int id = blockIdx.x;
    const int sid = (id & 7) * 96 + (id >> 3);
    const int bm = (sid / 12) * 128;
    const int bn = (sid % 12) * 192;

#define STAGE(nb_, kt_) do { \
    _Pragma("unroll") \
    for (int j_ = 0; j_ < 2; ++j_) { \
        const int idx_ = j_ * 256 + tid; \
        const int row_ = idx_ >> 2; \
        const int c_ = (idx_ & 3) ^ ((row_ >> 1) & 3); \
        GLOAD_LDS16(A + (size_t)(bm + row_) * K + (kt_) * 32 + c_ * 8, \
                    (char*)lds + (nb_) * (PBUF * 2) + j_ * 4096 + tid * 16); \
    } \
    _Pragma("unroll") \
    for (int j_ = 0; j_ < 3; ++j_) { \
        const int idx_ = j_ * 256 + tid; \
        const int row_ = idx_ >> 2; \
        const int c_ = (idx_ & 3) ^ ((row_ >> 1) & 3); \
        GLOAD_LDS16(Bt + (size_t)(bn + row_) * K + (kt_) * 32 + c_ * 8, \
                    (char*)lds + (nb_) * (PBUF * 2) + 8192 + j_ * 4096 + tid * 16); \
    } } while (0)

    f32x4 acc[4][6];
#pragma unroll
    for (int i = 0; i < 4; ++i)
#pragma unroll
        for (int j = 0; j < 6; ++j) acc[i][j] = (f32x4){0.f, 0.f, 0.f, 0.f};

    STAGE(0, 0);
    __builtin_amdgcn_sched_barrier(0);
    vmcnt_asm<0>();
    SBAR();

    for (int kt = 0; kt < NT; ++kt) {
        const int cur = kt & 1;
        if (kt < NT - 1) {
            STAGE(cur ^ 1, kt + 1);
            __builtin_amdgcn_sched_barrier(0);
            vmcnt_asm<5>();   // drain kt's loads; kt+1's 5 stay in flight
            SBAR();
        } else {
            // tail: drain the last tile's in-flight loads
            __builtin_amdgcn_sched_barrier(0);
            vmcnt_asm<0>();
            SBAR();
        }
        bf16x8 af[4], bfr[6];
#pragma unroll
        for (int mf = 0; mf < 4; ++mf) {
            const int row = wr * 64 + mf * 16 + lr;
            af[mf] = *reinterpret_cast<const bf16x8*>(
                &lds[cur * PBUF + row * 32 + ((lg ^ ((row >> 1) & 3)) << 3)]);
        }
#pragma unroll
        for (int nf = 0; nf < 6; ++nf) {
            const int row = wc * 96 + nf * 16 + lr;
            bfr[nf] = *reinterpret_cast<const bf16x8*>(
                &lds[cur * PBUF + 4096 + row * 32 + ((lg ^ ((row >> 1) & 3)) << 3)]);
        }
        __builtin_amdgcn_s_setprio(1);
#pragma unroll
        for (int mf = 0; mf < 4; ++mf)
#pragma unroll
            for (int nf = 0; nf < 6; ++nf)
                acc[mf][nf] = __builtin_amdgcn_mfma_f32_16x16x32_bf16(
                    af[mf], bfr[nf], acc[mf][nf], 0, 0, 0);
        __builtin_amdgcn_s_setprio(0);
        SBAR();
    }

    // epilogue: C/D layout col=lane&15, row=(lane>>4)*4+r (verified)
#pragma unroll
    for (int mf = 0; mf < 4; ++mf)
#pragma unroll
        for (int nf = 0; nf < 6; ++nf) {
            const int col = bn + wc * 96 + nf * 16 + lr;
#pragma unroll
            for (int r = 0; r < 4; ++r) {
                const int row = bm + wr * 64 + mf * 16 + lg * 4 + r;
                Cout[(size_t)row * 2304 + col] = f2bf(acc[mf][nf][r]);
            }
        }
#undef STAGE
}

// =====================================================================
// Big-tile GEMM (gemm2): tile 256x96, grid exactly 256, 4-phase K-loop.
// =====================================================================
template<int NTN, int NFRAG, int BROWS, int K, bool BF16_OUT>
__global__ __launch_bounds__(512, 2) void gemm_bigtile_kernel(const u16* __restrict__ A,
                                                              const u16* __restrict__ Bt,
                                                              void* __restrict__ Cout,
                                                              const float* __restrict__ bias) {
    constexpr int BN = NFRAG * 32;
    constexpr int N = NTN * BN;
    constexpr int NT = K / 64;
    constexpr int PA = 256 * 32;
    constexpr int PB = BROWS * 32;
    constexpr int PKS = PA + PB;
    constexpr int PBUF = 2 * PKS;
    constexpr int BFULL = (BROWS * 4) / 512;
    constexpr int BREM = (BROWS * 4) % 512;
    __shared__ u16 lds[2 * PBUF];

    const int tid = threadIdx.x;
    const int wv = tid >> 6, lane = tid & 63;
    const int lr = lane & 15, lg = lane >> 4;
    const int wr = wv >> 1, wc = wv & 1;

    const int id = blockIdx.x;
    const int sid = (id & 7) * 32 + (id >> 3);
    const int bm = (sid / NTN) * 256;
    const int bn = (sid % NTN) * BN;

#define PL(buf_, ks_, mat_) ((buf_) * PBUF + (ks_) * PKS + (mat_) * PA)

#define STAGE_A(nb_, kt_, ks_) do { \
    _Pragma("unroll") \
    for (int j_ = 0; j_ < 2; ++j_) { \
        const int idx_ = j_ * 512 + tid; \
        const int row_ = idx_ >> 2; \
        const int c_ = (idx_ & 3) ^ ((row_ >> 1) & 3); \
        GLOAD_LDS16(A + (size_t)(bm + row_) * K + (kt_) * 64 + (ks_) * 32 + c_ * 8, \
                    (char*)lds + PL((nb_), (ks_), 0) * 2 + j_ * 8192 + tid * 16); \
    } } while (0)

#define STAGE_B(nb_, kt_, ks_) do { \
    _Pragma("unroll") \
    for (int j_ = 0; j_ < BFULL; ++j_) { \
        const int idx_ = j_ * 512 + tid; \
        const int row_ = idx_ >> 2; \
        const int c_ = (idx_ & 3) ^ ((row_ >> 1) & 3); \
        GLOAD_LDS16(Bt + (size_t)(bn + row_) * K + (kt_) * 64 + (ks_) * 32 + c_ * 8, \
                    (char*)lds + PL((nb_), (ks_), 1) * 2 + j_ * 8192 + tid * 16); \
    } \
    if constexpr (BREM != 0) { \
        if (tid < BREM) { \
            const int idx_ = BFULL * 512 + tid; \
            const int row_ = idx_ >> 2; \
            const int c_ = (idx_ & 3) ^ ((row_ >> 1) & 3); \
            GLOAD_LDS16(Bt + (size_t)(bn + row_) * K + (kt_) * 64 + (ks_) * 32 + c_ * 8, \
                        (char*)lds + PL((nb_), (ks_), 1) * 2 + BFULL * 8192 + tid * 16); \
        } \
    } } while (0)

#define LDA(mh_, ks_, cur_) do { \
    _Pragma("unroll") \
    for (int f_ = 0; f_ < 2; ++f_) { \
        const int row_ = wr * 64 + (mh_) * 32 + f_ * 16 + lr; \
        af[f_] = *reinterpret_cast<const bf16x8*>( \
            &lds[PL((cur_), (ks_), 0) + row_ * 32 + ((lg ^ ((row_ >> 1) & 3)) << 3)]); \
    } } while (0)

#define LDB(ks_, cur_) do { \
    _Pragma("unroll") \
    for (int nf_ = 0; nf_ < NFRAG; ++nf_) { \
        const int row_ = wc * (NFRAG * 16) + nf_ * 16 + lr; \
        bfr[nf_] = *reinterpret_cast<const bf16x8*>( \
            &lds[PL((cur_), (ks_), 1) + row_ * 32 + ((lg ^ ((row_ >> 1) & 3)) << 3)]); \
    } } while (0)

#define MFMAQ(mh_) do { \
    __builtin_amdgcn_s_setprio(1); \
    _Pragma("unroll") \
    for (int f_ = 0; f_ < 2; ++f_) \
    _Pragma("unroll") \
    for (int nf_ = 0; nf_ < NFRAG; ++nf_) \
        acc[(mh_) * 2 + f_][nf_] = __builtin_amdgcn_mfma_f32_16x16x32_bf16( \
            af[f_], bfr[nf_], acc[(mh_) * 2 + f_][nf_], 0, 0, 0); \
    __builtin_amdgcn_s_setprio(0); } while (0)

#define WAITHALF() do { \
    __builtin_amdgcn_sched_barrier(0); \
    if constexpr (BREM != 0) { \
        if (wv < BREM / 64) vmcnt_asm<2 + BFULL + 1>(); \
        else vmcnt_asm<2 + BFULL>(); \
    } else { \
        vmcnt_asm<2 + BFULL>(); \
    } } while (0)

    f32x4 acc[4][NFRAG];
#pragma unroll
    for (int i = 0; i < 4; ++i)
#pragma unroll
        for (int j = 0; j < NFRAG; ++j) acc[i][j] = (f32x4){0.f, 0.f, 0.f, 0.f};

    bf16x8 af[2], bfr[NFRAG];

    STAGE_A(0, 0, 0); STAGE_B(0, 0, 0); STAGE_A(0, 0, 1); STAGE_B(0, 0, 1);
    __builtin_amdgcn_sched_barrier(0);
    vmcnt_asm<0>();
    SBAR();

    for (int kt = 0; kt < NT - 1; ++kt) {
        const int cur = kt & 1, nxt = cur ^ 1;
        LDB(0, cur); LDA(0, 0, cur);
        STAGE_A(nxt, kt + 1, 0);
        SBAR(); MFMAQ(0); SBAR();
        LDA(1, 0, cur);
        STAGE_B(nxt, kt + 1, 0);
        WAITHALF();
        SBAR(); MFMAQ(1); SBAR();
        LDB(1, cur); LDA(0, 1, cur);
        STAGE_A(nxt, kt + 1, 1);
        SBAR(); MFMAQ(0); SBAR();
        LDA(1, 1, cur);
        STAGE_B(nxt, kt + 1, 1);
        WAITHALF();
        SBAR(); MFMAQ(1); SBAR();
    }
    {
        const int cur = (NT - 1) & 1;
        LDB(0, cur); LDA(0, 0, cur); SBAR(); MFMAQ(0); SBAR();
        LDA(1, 0, cur);
        __builtin_amdgcn_sched_barrier(0);
        vmcnt_asm<0>();
        SBAR(); MFMAQ(1); SBAR();
        LDB(1, cur); LDA(0, 1, cur); SBAR(); MFMAQ(0); SBAR();
        LDA(1, 1, cur); SBAR(); MFMAQ(1);
    }

#pragma unroll
    for (int mf = 0; mf < 4; ++mf)
#pragma unroll
        for (int nf = 0; nf < NFRAG; ++nf) {
            const int col = bn + wc * (NFRAG * 16) + nf * 16 + lr;
            const float bv = BF16_OUT ? 0.f : bias[col];
#pragma unroll
            for (int r = 0; r < 4; ++r) {
                const int row = bm + wr * 64 + mf * 16 + lg * 4 + r;
                if (BF16_OUT)
                    ((u16*)Cout)[(size_t)row * N + col] = f2bf(acc[mf][nf][r]);
                else
                    ((float*)Cout)[(size_t)row * N + col] = acc[mf][nf][r] + bv;
            }
        }
#undef PL
#undef STAGE_A
#undef STAGE_B
#undef LDA
#undef LDB
#undef MFMAQ
#undef WAITHALF
}

// ---------------- fused rotary (q,k) + V transpose ----------------
__global__ __launch_bounds__(256) void rot_vtrans_kernel(u16* __restrict__ qkv,
                                                         const float* __restrict__ pos,
                                                         u16* __restrict__ Vt) {
    __shared__ u16 tile[64][72];
    const int bid = blockIdx.x;
    if (bid < 6144) {
        int t = bid * 256 + threadIdx.x;
        int row = t / 192;
        int col = (t % 192) * 8;
        int n = row & 1023;
        int i0 = (col & 63) >> 1;
        const float qs = (col < 768) ? 0.18033688f : 1.0f;  // 0.125 * log2(e)
        const float* pn = pos + (size_t)n * 64;
        u16* p = qkv + (size_t)row * 2304 + col;
        bf16x8 v = *reinterpret_cast<bf16x8*>(p);
        u16 o[8];
#pragma unroll
        for (int j = 0; j < 4; ++j) {
            float s = pn[i0 + j], c = pn[32 + i0 + j];
            float x0 = bf2f((u16)v[2 * j]), x1 = bf2f((u16)v[2 * j + 1]);
            o[2 * j]     = f2bf((x0 * c - x1 * s) * qs);
            o[2 * j + 1] = f2bf((x1 * c + x0 * s) * qs);
        }
        *reinterpret_cast<bf16x8*>(p) = *reinterpret_cast<bf16x8*>(o);
    } else {
        int u = bid - 6144;
        int nt = u & 15;
        int bh = u >> 4;
        int b = bh / 12, h = bh % 12;
        int tid = threadIdx.x;
        int rr = tid >> 3, cc = (tid & 7) * 8;
#pragma unroll
        for (int it = 0; it < 2; ++it) {
            int nloc = it * 32 + rr;
            const u16* src = qkv + (size_t)(b * 1024 + nt * 64 + nloc) * 2304 + 1536 + h * 64 + cc;
            bf16x8 v = *reinterpret_cast<const bf16x8*>(src);
#pragma unroll
            for (int j = 0; j < 8; ++j) tile[nloc][cc + j] = (u16)v[j];
        }
        __syncthreads();
#pragma unroll
        for (int it = 0; it < 2; ++it) {
            int d = it * 32 + rr;
            u16 o[8];
#pragma unroll
            for (int j = 0; j < 8; ++j) o[j] = tile[cc + j][d];
            *reinterpret_cast<bf16x8*>(Vt + (size_t)(bh * 64 + d) * 1024 + nt * 64 + cc) =
                *reinterpret_cast<bf16x8*>(o);
        }
    }
}

// ---------------- flash attention v7: 4 waves x 32 q, 3-buf 2-deep, raw barriers ----------------
__global__ __launch_bounds__(256, 3) void attn_kernel(const u16* __restrict__ qkv,
                                                      const u16* __restrict__ Vt,
                                                      u16* __restrict__ attn_out) {
    __shared__ u16 Ks[3][64 * 64];
    __shared__ u16 Vs[3][64 * 64];
    const int d_ = blockIdx.x;
    const int bh = ((d_ >> 3) >> 3) * 8 + (d_ & 7);  // bh%8 == blockIdx%8 == XCD
    const int qt = (d_ >> 3) & 7;
    const int b = bh / 12, h = bh % 12;
    const int tid = threadIdx.x;
    const int w = tid >> 6, lr = tid & 15, lg = (tid >> 4) & 3;

    bf16x8 qf[2][2];
#pragma unroll
    for (int q = 0; q < 2; ++q)
#pragma unroll
        for (int ds = 0; ds < 2; ++ds)
            qf[q][ds] = *reinterpret_cast<const bf16x8*>(
                &qkv[(size_t)(b * 1024 + qt * 128 + w * 32 + q * 16 + lr) * 2304 +
                     h * 64 + ds * 32 + lg * 8]);

    f32x4 o[2][4];
#pragma unroll
    for (int q = 0; q < 2; ++q)
#pragma unroll
        for (int i = 0; i < 4; ++i) o[q][i] = (f32x4){0.f, 0.f, 0.f, 0.f};
    float lsum[2] = {0.f, 0.f};

#define STAGE_KV(nb, kt_) do { \
    _Pragma("unroll") \
    for (int j_ = 0; j_ < 2; ++j_) { \
        const int idx_ = j_ * 256 + tid; \
        const int row_ = idx_ >> 3; \
        const int sc_ = ((idx_ & 7) ^ (row_ & 7)) * 8; \
        const int rk_ = (row_ & 0x20) | ((row_ & 0x0C) << 1) | ((row_ & 0x10) >> 2) | (row_ & 3); \
        GLOAD_LDS16(qkv + (size_t)(b * 1024 + (kt_) * 64 + rk_) * 2304 + 768 + h * 64 + sc_, \
                    (char*)Ks[nb] + idx_ * 16); \
        GLOAD_LDS16(Vt + (size_t)(bh * 64 + row_) * 1024 + (kt_) * 64 + sc_, \
                    (char*)Vs[nb] + idx_ * 16); \
    } } while (0)

    // prologue: two stages in flight (kt=0 into buf0, kt=1 into buf1)
    STAGE_KV(0, 0);
    STAGE_KV(1, 1);

    const int rsw = lr & 7;

    for (int kt = 0; kt < 16; ++kt) {
        const int cur = kt % 3;
        if (kt < 14) {
            STAGE_KV((kt + 2) % 3, kt + 2);
            __builtin_amdgcn_sched_barrier(0);
            vmcnt_asm<8>();   // kt's 4 loads done; kt+1,kt+2 (8) stay in flight
        } else if (kt == 14) {
            __builtin_amdgcn_sched_barrier(0);
            vmcnt_asm<4>();
        } else {
            __builtin_amdgcn_sched_barrier(0);
            vmcnt_asm<0>();
        }
        SBAR();

        f32x4 s[2][4];
        __builtin_amdgcn_s_setprio(1);
#pragma unroll
        for (int kf = 0; kf < 4; ++kf) {
            bf16x8 k0 = *reinterpret_cast<const bf16x8*>(
                &Ks[cur][(kf * 16 + lr) * 64 + ((lg ^ rsw) * 8)]);
            bf16x8 k1 = *reinterpret_cast<const bf16x8*>(
                &Ks[cur][(kf * 16 + lr) * 64 + (((4 + lg) ^ rsw) * 8)]);
#pragma unroll
            for (int q = 0; q < 2; ++q) {
                f32x4 a = __builtin_amdgcn_mfma_f32_16x16x32_bf16(
                    k0, qf[q][0], (f32x4){0.f, 0.f, 0.f, 0.f}, 0, 0, 0);
                s[q][kf] = __builtin_amdgcn_mfma_f32_16x16x32_bf16(k1, qf[q][1], a, 0, 0, 0);
            }
        }
        __builtin_amdgcn_s_setprio(0);

        union { u32 wd[4]; bf16x8 v; } pk[2][2];
#pragma unroll
        for (int q = 0; q < 2; ++q) {
#pragma unroll
            for (int kf = 0; kf < 4; ++kf)
#pragma unroll
                for (int r = 0; r < 4; ++r) s[q][kf][r] = __builtin_amdgcn_exp2f(s[q][kf][r]);
            float t0 = (s[q][0][0] + s[q][0][1]) + (s[q][0][2] + s[q][0][3]);
            float t1 = (s[q][1][0] + s[q][1][1]) + (s[q][1][2] + s[q][1][3]);
            float t2 = (s[q][2][0] + s[q][2][1]) + (s[q][2][2] + s[q][2][3]);
            float t3 = (s[q][3][0] + s[q][3][1]) + (s[q][3][2] + s[q][3][3]);
            lsum[q] += (t0 + t1) + (t2 + t3);
#pragma unroll
            for (int ks = 0; ks < 2; ++ks) {
                pk[q][ks].wd[0] = cvt_pk_bf16(s[q][2 * ks][0], s[q][2 * ks][1]);
                pk[q][ks].wd[1] = cvt_pk_bf16(s[q][2 * ks][2], s[q][2 * ks][3]);
                pk[q][ks].wd[2] = cvt_pk_bf16(s[q][2 * ks + 1][0], s[q][2 * ks + 1][1]);
                pk[q][ks].wd[3] = cvt_pk_bf16(s[q][2 * ks + 1][2], s[q][2 * ks + 1][3]);
            }
        }

        __builtin_amdgcn_s_setprio(1);
#pragma unroll
        for (int ks = 0; ks < 2; ++ks) {
#pragma unroll
            for (int df = 0; df < 4; ++df) {
                bf16x8 vb = *reinterpret_cast<const bf16x8*>(
                    &Vs[cur][(df * 16 + lr) * 64 + (((ks * 4 + lg) ^ rsw) * 8)]);
                o[0][df] = __builtin_amdgcn_mfma_f32_16x16x32_bf16(vb, pk[0][ks].v, o[0][df], 0, 0, 0);
                o[1][df] = __builtin_amdgcn_mfma_f32_16x16x32_bf16(vb, pk[1][ks].v, o[1][df], 0, 0, 0);
            }
        }
        __builtin_amdgcn_s_setprio(0);
        SBAR();
    }
#undef STAGE_KV

#pragma unroll
    for (int q = 0; q < 2; ++q) {
        float l = lsum[q];
        l += __shfl_xor(l, 16);
        l += __shfl_xor(l, 32);
        const float linv = 1.0f / l;
        u16* orow = attn_out +
            (size_t)(b * 1024 + qt * 128 + w * 32 + q * 16 + lr) * 768 + h * 64 + lg * 4;
#pragma unroll
        for (int df = 0; df < 4; ++df) {
            uint2 st;
            st.x = cvt_pk_bf16(o[q][df][0] * linv, o[q][df][1] * linv);
            st.y = cvt_pk_bf16(o[q][df][2] * linv, o[q][df][3] * linv);
            *reinterpret_cast<uint2*>(orow + df * 16) = st;
        }
    }
}

extern "C" void kernel_launch(void* const* d_in, const int* in_sizes, int n_in,
                              void* d_out, int out_size, void* d_ws, size_t ws_size,
                              hipStream_t stream) {
    (void)in_sizes; (void)n_in; (void)out_size; (void)ws_size;
    const float* x     = (const float*)d_in[0];   // [8,1024,768]
    const float* pos   = (const float*)d_in[1];   // [1,1024,64]
    const float* W_qkv = (const float*)d_in[2];   // [768,2304]
    const float* W_out = (const float*)d_in[3];   // [768,768]
    const float* b_out = (const float*)d_in[4];   // [768]
    float* out = (float*)d_out;                   // [8,1024,768]

    // workspace layout (bytes); Wqkv_t padded to 2336 rows, Wout_t to 800 rows
    char* ws = (char*)d_ws;
    u16* xb     = (u16*)(ws);                       // 8192x768   bf16 (12582912)
    u16* Wqkv_t = (u16*)(ws + 12582912);            // 2336x768   bf16 (3588096)
    u16* Wout_t = (u16*)(ws + 16171008);            // 800x768    bf16 (1228800)
    u16* qkv    = (u16*)(ws + 17399808);            // 8192x2304  bf16 (37748736)
    u16* Vt     = (u16*)(ws + 55148544);            // 96x64x1024 bf16 (12582912)
    u16* attn_o = (u16*)(ws + 67731456);            // 8192x768   bf16 (12582912)

    prep_kernel<<<5376, 256, 0, stream>>>(x, xb, W_qkv, Wqkv_t, W_out, Wout_t);
    // qkv = xb @ Wqkv^T : tile 128x192, grid 768 = 3 blocks/CU (best measured)
    gemm1_kernel<768><<<768, 256, 0, stream>>>(xb, Wqkv_t, qkv);
    rot_vtrans_kernel<<<7680, 256, 0, stream>>>(qkv, pos, Vt);
    attn_kernel<<<768, 256, 0, stream>>>(qkv, Vt, attn_o);
    // out = attn_o @ Wout^T + b : tile 256x96, grid exactly 256
    gemm_bigtile_kernel<8, 3, 128, 768, false><<<256, 512, 0, stream>>>(attn_o, Wout_t, out, b_out);
}

// Round 19
// 109.036 us; speedup vs baseline: 1.0241x; 1.0002x over previous
//
#include <hip/hip_runtime.h>
#include <hip/hip_bf16.h>

typedef __attribute__((ext_vector_type(8))) short bf16x8;
typedef __attribute__((ext_vector_type(4))) float f32x4;
typedef __attribute__((ext_vector_type(4))) unsigned short u16x4;
typedef unsigned short u16;
typedef unsigned int u32;

#define DEVINL __device__ __forceinline__

DEVINL u16 f2bf(float f) {
    union { float f; u32 u; } v; v.f = f;
    u32 r = v.u + 0x7FFFu + ((v.u >> 16) & 1u);
    return (u16)(r >> 16);
}
DEVINL float bf2f(u16 h) {
    union { u32 u; float f; } v; v.u = ((u32)h) << 16;
    return v.f;
}
DEVINL u32 cvt_pk_bf16(float lo, float hi) {
    u32 r;
    asm("v_cvt_pk_bf16_f32 %0, %1, %2" : "=v"(r) : "v"(lo), "v"(hi));
    return r;
}

template<int Nv> DEVINL void vmcnt_asm() {
    if constexpr (Nv == 0) asm volatile("s_waitcnt vmcnt(0)" ::: "memory");
    else if constexpr (Nv == 2) asm volatile("s_waitcnt vmcnt(2)" ::: "memory");
    else if constexpr (Nv == 3) asm volatile("s_waitcnt vmcnt(3)" ::: "memory");
    else if constexpr (Nv == 4) asm volatile("s_waitcnt vmcnt(4)" ::: "memory");
    else if constexpr (Nv == 5) asm volatile("s_waitcnt vmcnt(5)" ::: "memory");
    else if constexpr (Nv == 6) asm volatile("s_waitcnt vmcnt(6)" ::: "memory");
    else if constexpr (Nv == 7) asm volatile("s_waitcnt vmcnt(7)" ::: "memory");
    else if constexpr (Nv == 8) asm volatile("s_waitcnt vmcnt(8)" ::: "memory");
    else asm volatile("s_waitcnt vmcnt(4)" ::: "memory");
}

// async global->LDS, 16B per lane; LDS dest = wave-uniform base + lane*16
#define GLOAD_LDS16(g, l) __builtin_amdgcn_global_load_lds( \
    (const __attribute__((address_space(1))) void*)(g), \
    (__attribute__((address_space(3))) void*)(l), 16, 0, 0)

#define SBAR() do { \
    __builtin_amdgcn_sched_barrier(0); \
    __builtin_amdgcn_s_barrier(); \
    __builtin_amdgcn_sched_barrier(0); } while (0)

// ---------------- fused prep: x->bf16 cvt + both weight transposes ----------------
__global__ __launch_bounds__(256) void prep_kernel(const float* __restrict__ x,
                                                   u16* __restrict__ xb,
                                                   const float* __restrict__ W_qkv,
                                                   u16* __restrict__ Wqkv_t,
                                                   const float* __restrict__ W_out,
                                                   u16* __restrict__ Wout_t) {
    __shared__ float tile[32][33];
    const int bid = blockIdx.x;
    if (bid < 3072) {
        int t = bid * 256 + threadIdx.x;
        const float4 v0 = reinterpret_cast<const float4*>(x)[t * 2];
        const float4 v1 = reinterpret_cast<const float4*>(x)[t * 2 + 1];
        u16 o[8];
        o[0] = f2bf(v0.x); o[1] = f2bf(v0.y); o[2] = f2bf(v0.z); o[3] = f2bf(v0.w);
        o[4] = f2bf(v1.x); o[5] = f2bf(v1.y); o[6] = f2bf(v1.z); o[7] = f2bf(v1.w);
        *reinterpret_cast<bf16x8*>(xb + (size_t)t * 8) = *reinterpret_cast<bf16x8*>(o);
        return;
    }
    const float* in; u16* out; int R, C, bx, by;
    if (bid < 4800) {
        int u = bid - 3072; in = W_qkv; out = Wqkv_t; R = 768; C = 2304;
        bx = u % 72; by = u / 72;
    } else {
        int u = bid - 4800; in = W_out; out = Wout_t; R = 768; C = 768;
        bx = u % 24; by = u / 24;
    }
    int c0 = bx * 32, r0 = by * 32;
    int tx = threadIdx.x & 31, ty = threadIdx.x >> 5;
#pragma unroll
    for (int i = 0; i < 4; ++i)
        tile[ty + i * 8][tx] = in[(size_t)(r0 + ty + i * 8) * C + c0 + tx];
    __syncthreads();
#pragma unroll
    for (int i = 0; i < 4; ++i)
        out[(size_t)(c0 + ty + i * 8) * R + r0 + tx] = f2bf(tile[tx][ty + i * 8]);
}

// =====================================================================
// GEMM1 (r12 config, best measured 43.0 us): tile 128x192, BK=32,
// 4 waves (2Mx2N), wave 64x96 (mf4 x nf6). Grid 768 = 3 blocks/CU,
// counted vmcnt(5); tail iteration drains vmcnt(0). Chunk swizzle
// c^=(row>>1)&3 on both sides (measured 0 conflicts).
// =====================================================================
template<int K>
__global__ __launch_bounds__(256, 3) void gemm1_kernel(const u16* __restrict__ A,
                                                       const u16* __restrict__ Bt,
                                                       u16* __restrict__ Cout) {
    constexpr int NT = K / 32;
    constexpr int PBUF = (128 + 192) * 32;   // elems per buffer (A|B planes)
    __shared__ u16 lds[2 * PBUF];

    const int tid = threadIdx.x;
    const int wv = tid >> 6, lane = tid & 63;
    const int lr = lane & 15, lg = lane >> 4;
    const int wr = wv >> 1, wc = wv & 1;

    // XCD-aware bijective swizzle over 768 = 8 x 96
    const int id = blockIdx.x;
    const int sid = (id & 7) * 96 + (id >> 3);
    const int bm = (sid / 12) * 128;
    const int bn = (sid % 12) * 192;

#define STAGE(nb_, kt_) do { \
    _Pragma("unroll") \
    for (int j_ = 0; j_ < 2; ++j_) { \
        const int idx_ = j_ * 256 + tid; \
        const int row_ = idx_ >> 2; \
        const int c_ = (idx_ & 3) ^ ((row_ >> 1) & 3); \
        GLOAD_LDS16(A + (size_t)(bm + row_) * K + (kt_) * 32 + c_ * 8, \
                    (char*)lds + (nb_) * (PBUF * 2) + j_ * 4096 + tid * 16); \
    } \
    _Pragma("unroll") \
    for (int j_ = 0; j_ < 3; ++j_) { \
        const int idx_ = j_ * 256 + tid; \
        const int row_ = idx_ >> 2; \
        const int c_ = (idx_ & 3) ^ ((row_ >> 1) & 3); \
        GLOAD_LDS16(Bt + (size_t)(bn + row_) * K + (kt_) * 32 + c_ * 8, \
                    (char*)lds + (nb_) * (PBUF * 2) + 8192 + j_ * 4096 + tid * 16); \
    } } while (0)

    f32x4 acc[4][6];
#pragma unroll
    for (int i = 0; i < 4; ++i)
#pragma unroll
        for (int j = 0; j < 6; ++j) acc[i][j] = (f32x4){0.f, 0.f, 0.f, 0.f};

    STAGE(0, 0);
    __builtin_amdgcn_sched_barrier(0);
    vmcnt_asm<0>();
    SBAR();

    for (int kt = 0; kt < NT; ++kt) {
        const int cur = kt & 1;
        if (kt < NT - 1) {
            STAGE(cur ^ 1, kt + 1);
            __builtin_amdgcn_sched_barrier(0);
            vmcnt_asm<5>();   // drain kt's loads; kt+1's 5 stay in flight
            SBAR();
        } else {
            // tail: drain the last tile's in-flight loads
            __builtin_amdgcn_sched_barrier(0);
            vmcnt_asm<0>();
            SBAR();
        }
        bf16x8 af[4], bfr[6];
#pragma unroll
        for (int mf = 0; mf < 4; ++mf) {
            const int row = wr * 64 + mf * 16 + lr;
            af[mf] = *reinterpret_cast<const bf16x8*>(
                &lds[cur * PBUF + row * 32 + ((lg ^ ((row >> 1) & 3)) << 3)]);
        }
#pragma unroll
        for (int nf = 0; nf < 6; ++nf) {
            const int row = wc * 96 + nf * 16 + lr;
            bfr[nf] = *reinterpret_cast<const bf16x8*>(
                &lds[cur * PBUF + 4096 + row * 32 + ((lg ^ ((row >> 1) & 3)) << 3)]);
        }
        __builtin_amdgcn_s_setprio(1);
#pragma unroll
        for (int mf = 0; mf < 4; ++mf)
#pragma unroll
            for (int nf = 0; nf < 6; ++nf)
                acc[mf][nf] = __builtin_amdgcn_mfma_f32_16x16x32_bf16(
                    af[mf], bfr[nf], acc[mf][nf], 0, 0, 0);
        __builtin_amdgcn_s_setprio(0);
        SBAR();
    }

    // epilogue: C/D layout col=lane&15, row=(lane>>4)*4+r (verified)
#pragma unroll
    for (int mf = 0; mf < 4; ++mf)
#pragma unroll
        for (int nf = 0; nf < 6; ++nf) {
            const int col = bn + wc * 96 + nf * 16 + lr;
#pragma unroll
            for (int r = 0; r < 4; ++r) {
                const int row = bm + wr * 64 + mf * 16 + lg * 4 + r;
                Cout[(size_t)row * 2304 + col] = f2bf(acc[mf][nf][r]);
            }
        }
#undef STAGE
}

// =====================================================================
// Big-tile GEMM (gemm2): tile 256x96, grid exactly 256, 4-phase K-loop.
// =====================================================================
template<int NTN, int NFRAG, int BROWS, int K, bool BF16_OUT>
__global__ __launch_bounds__(512, 2) void gemm_bigtile_kernel(const u16* __restrict__ A,
                                                              const u16* __restrict__ Bt,
                                                              void* __restrict__ Cout,
                                                              const float* __restrict__ bias) {
    constexpr int BN = NFRAG * 32;
    constexpr int N = NTN * BN;
    constexpr int NT = K / 64;
    constexpr int PA = 256 * 32;
    constexpr int PB = BROWS * 32;
    constexpr int PKS = PA + PB;
    constexpr int PBUF = 2 * PKS;
    constexpr int BFULL = (BROWS * 4) / 512;
    constexpr int BREM = (BROWS * 4) % 512;
    __shared__ u16 lds[2 * PBUF];

    const int tid = threadIdx.x;
    const int wv = tid >> 6, lane = tid & 63;
    const int lr = lane & 15, lg = lane >> 4;
    const int wr = wv >> 1, wc = wv & 1;

    const int id = blockIdx.x;
    const int sid = (id & 7) * 32 + (id >> 3);
    const int bm = (sid / NTN) * 256;
    const int bn = (sid % NTN) * BN;

#define PL(buf_, ks_, mat_) ((buf_) * PBUF + (ks_) * PKS + (mat_) * PA)

#define STAGE_A(nb_, kt_, ks_) do { \
    _Pragma("unroll") \
    for (int j_ = 0; j_ < 2; ++j_) { \
        const int idx_ = j_ * 512 + tid; \
        const int row_ = idx_ >> 2; \
        const int c_ = (idx_ & 3) ^ ((row_ >> 1) & 3); \
        GLOAD_LDS16(A + (size_t)(bm + row_) * K + (kt_) * 64 + (ks_) * 32 + c_ * 8, \
                    (char*)lds + PL((nb_), (ks_), 0) * 2 + j_ * 8192 + tid * 16); \
    } } while (0)

#define STAGE_B(nb_, kt_, ks_) do { \
    _Pragma("unroll") \
    for (int j_ = 0; j_ < BFULL; ++j_) { \
        const int idx_ = j_ * 512 + tid; \
        const int row_ = idx_ >> 2; \
        const int c_ = (idx_ & 3) ^ ((row_ >> 1) & 3); \
        GLOAD_LDS16(Bt + (size_t)(bn + row_) * K + (kt_) * 64 + (ks_) * 32 + c_ * 8, \
                    (char*)lds + PL((nb_), (ks_), 1) * 2 + j_ * 8192 + tid * 16); \
    } \
    if constexpr (BREM != 0) { \
        if (tid < BREM) { \
            const int idx_ = BFULL * 512 + tid; \
            const int row_ = idx_ >> 2; \
            const int c_ = (idx_ & 3) ^ ((row_ >> 1) & 3); \
            GLOAD_LDS16(Bt + (size_t)(bn + row_) * K + (kt_) * 64 + (ks_) * 32 + c_ * 8, \
                        (char*)lds + PL((nb_), (ks_), 1) * 2 + BFULL * 8192 + tid * 16); \
        } \
    } } while (0)

#define LDA(mh_, ks_, cur_) do { \
    _Pragma("unroll") \
    for (int f_ = 0; f_ < 2; ++f_) { \
        const int row_ = wr * 64 + (mh_) * 32 + f_ * 16 + lr; \
        af[f_] = *reinterpret_cast<const bf16x8*>( \
            &lds[PL((cur_), (ks_), 0) + row_ * 32 + ((lg ^ ((row_ >> 1) & 3)) << 3)]); \
    } } while (0)

#define LDB(ks_, cur_) do { \
    _Pragma("unroll") \
    for (int nf_ = 0; nf_ < NFRAG; ++nf_) { \
        const int row_ = wc * (NFRAG * 16) + nf_ * 16 + lr; \
        bfr[nf_] = *reinterpret_cast<const bf16x8*>( \
            &lds[PL((cur_), (ks_), 1) + row_ * 32 + ((lg ^ ((row_ >> 1) & 3)) << 3)]); \
    } } while (0)

#define MFMAQ(mh_) do { \
    __builtin_amdgcn_s_setprio(1); \
    _Pragma("unroll") \
    for (int f_ = 0; f_ < 2; ++f_) \
    _Pragma("unroll") \
    for (int nf_ = 0; nf_ < NFRAG; ++nf_) \
        acc[(mh_) * 2 + f_][nf_] = __builtin_amdgcn_mfma_f32_16x16x32_bf16( \
            af[f_], bfr[nf_], acc[(mh_) * 2 + f_][nf_], 0, 0, 0); \
    __builtin_amdgcn_s_setprio(0); } while (0)

#define WAITHALF() do { \
    __builtin_amdgcn_sched_barrier(0); \
    if constexpr (BREM != 0) { \
        if (wv < BREM / 64) vmcnt_asm<2 + BFULL + 1>(); \
        else vmcnt_asm<2 + BFULL>(); \
    } else { \
        vmcnt_asm<2 + BFULL>(); \
    } } while (0)

    f32x4 acc[4][NFRAG];
#pragma unroll
    for (int i = 0; i < 4; ++i)
#pragma unroll
        for (int j = 0; j < NFRAG; ++j) acc[i][j] = (f32x4){0.f, 0.f, 0.f, 0.f};

    bf16x8 af[2], bfr[NFRAG];

    STAGE_A(0, 0, 0); STAGE_B(0, 0, 0); STAGE_A(0, 0, 1); STAGE_B(0, 0, 1);
    __builtin_amdgcn_sched_barrier(0);
    vmcnt_asm<0>();
    SBAR();

    for (int kt = 0; kt < NT - 1; ++kt) {
        const int cur = kt & 1, nxt = cur ^ 1;
        LDB(0, cur); LDA(0, 0, cur);
        STAGE_A(nxt, kt + 1, 0);
        SBAR(); MFMAQ(0); SBAR();
        LDA(1, 0, cur);
        STAGE_B(nxt, kt + 1, 0);
        WAITHALF();
        SBAR(); MFMAQ(1); SBAR();
        LDB(1, cur); LDA(0, 1, cur);
        STAGE_A(nxt, kt + 1, 1);
        SBAR(); MFMAQ(0); SBAR();
        LDA(1, 1, cur);
        STAGE_B(nxt, kt + 1, 1);
        WAITHALF();
        SBAR(); MFMAQ(1); SBAR();
    }
    {
        const int cur = (NT - 1) & 1;
        LDB(0, cur); LDA(0, 0, cur); SBAR(); MFMAQ(0); SBAR();
        LDA(1, 0, cur);
        __builtin_amdgcn_sched_barrier(0);
        vmcnt_asm<0>();
        SBAR(); MFMAQ(1); SBAR();
        LDB(1, cur); LDA(0, 1, cur); SBAR(); MFMAQ(0); SBAR();
        LDA(1, 1, cur); SBAR(); MFMAQ(1);
    }

#pragma unroll
    for (int mf = 0; mf < 4; ++mf)
#pragma unroll
        for (int nf = 0; nf < NFRAG; ++nf) {
            const int col = bn + wc * (NFRAG * 16) + nf * 16 + lr;
            const float bv = BF16_OUT ? 0.f : bias[col];
#pragma unroll
            for (int r = 0; r < 4; ++r) {
                const int row = bm + wr * 64 + mf * 16 + lg * 4 + r;
                if (BF16_OUT)
                    ((u16*)Cout)[(size_t)row * N + col] = f2bf(acc[mf][nf][r]);
                else
                    ((float*)Cout)[(size_t)row * N + col] = acc[mf][nf][r] + bv;
            }
        }
#undef PL
#undef STAGE_A
#undef STAGE_B
#undef LDA
#undef LDB
#undef MFMAQ
#undef WAITHALF
}

// ---------------- fused rotary (q,k) + V transpose ----------------
__global__ __launch_bounds__(256) void rot_vtrans_kernel(u16* __restrict__ qkv,
                                                         const float* __restrict__ pos,
                                                         u16* __restrict__ Vt) {
    __shared__ u16 tile[64][72];
    const int bid = blockIdx.x;
    if (bid < 6144) {
        int t = bid * 256 + threadIdx.x;
        int row = t / 192;
        int col = (t % 192) * 8;
        int n = row & 1023;
        int i0 = (col & 63) >> 1;
        const float qs = (col < 768) ? 0.18033688f : 1.0f;  // 0.125 * log2(e)
        const float* pn = pos + (size_t)n * 64;
        u16* p = qkv + (size_t)row * 2304 + col;
        bf16x8 v = *reinterpret_cast<bf16x8*>(p);
        u16 o[8];
#pragma unroll
        for (int j = 0; j < 4; ++j) {
            float s = pn[i0 + j], c = pn[32 + i0 + j];
            float x0 = bf2f((u16)v[2 * j]), x1 = bf2f((u16)v[2 * j + 1]);
            o[2 * j]     = f2bf((x0 * c - x1 * s) * qs);
            o[2 * j + 1] = f2bf((x1 * c + x0 * s) * qs);
        }
        *reinterpret_cast<bf16x8*>(p) = *reinterpret_cast<bf16x8*>(o);
    } else {
        int u = bid - 6144;
        int nt = u & 15;
        int bh = u >> 4;
        int b = bh / 12, h = bh % 12;
        int tid = threadIdx.x;
        int rr = tid >> 3, cc = (tid & 7) * 8;
#pragma unroll
        for (int it = 0; it < 2; ++it) {
            int nloc = it * 32 + rr;
            const u16* src = qkv + (size_t)(b * 1024 + nt * 64 + nloc) * 2304 + 1536 + h * 64 + cc;
            bf16x8 v = *reinterpret_cast<const bf16x8*>(src);
#pragma unroll
            for (int j = 0; j < 8; ++j) tile[nloc][cc + j] = (u16)v[j];
        }
        __syncthreads();
#pragma unroll
        for (int it = 0; it < 2; ++it) {
            int d = it * 32 + rr;
            u16 o[8];
#pragma unroll
            for (int j = 0; j < 8; ++j) o[j] = tile[cc + j][d];
            *reinterpret_cast<bf16x8*>(Vt + (size_t)(bh * 64 + d) * 1024 + nt * 64 + cc) =
                *reinterpret_cast<bf16x8*>(o);
        }
    }
}

// ---------------- flash attention v7: 4 waves x 32 q, 3-buf 2-deep, raw barriers ----------------
__global__ __launch_bounds__(256, 3) void attn_kernel(const u16* __restrict__ qkv,
                                                      const u16* __restrict__ Vt,
                                                      u16* __restrict__ attn_out) {
    __shared__ u16 Ks[3][64 * 64];
    __shared__ u16 Vs[3][64 * 64];
    const int d_ = blockIdx.x;
    const int bh = ((d_ >> 3) >> 3) * 8 + (d_ & 7);  // bh%8 == blockIdx%8 == XCD
    const int qt = (d_ >> 3) & 7;
    const int b = bh / 12, h = bh % 12;
    const int tid = threadIdx.x;
    const int w = tid >> 6, lr = tid & 15, lg = (tid >> 4) & 3;

    bf16x8 qf[2][2];
#pragma unroll
    for (int q = 0; q < 2; ++q)
#pragma unroll
        for (int ds = 0; ds < 2; ++ds)
            qf[q][ds] = *reinterpret_cast<const bf16x8*>(
                &qkv[(size_t)(b * 1024 + qt * 128 + w * 32 + q * 16 + lr) * 2304 +
                     h * 64 + ds * 32 + lg * 8]);

    f32x4 o[2][4];
#pragma unroll
    for (int q = 0; q < 2; ++q)
#pragma unroll
        for (int i = 0; i < 4; ++i) o[q][i] = (f32x4){0.f, 0.f, 0.f, 0.f};
    float lsum[2] = {0.f, 0.f};

#define STAGE_KV(nb, kt_) do { \
    _Pragma("unroll") \
    for (int j_ = 0; j_ < 2; ++j_) { \
        const int idx_ = j_ * 256 + tid; \
        const int row_ = idx_ >> 3; \
        const int sc_ = ((idx_ & 7) ^ (row_ & 7)) * 8; \
        const int rk_ = (row_ & 0x20) | ((row_ & 0x0C) << 1) | ((row_ & 0x10) >> 2) | (row_ & 3); \
        GLOAD_LDS16(qkv + (size_t)(b * 1024 + (kt_) * 64 + rk_) * 2304 + 768 + h * 64 + sc_, \
                    (char*)Ks[nb] + idx_ * 16); \
        GLOAD_LDS16(Vt + (size_t)(bh * 64 + row_) * 1024 + (kt_) * 64 + sc_, \
                    (char*)Vs[nb] + idx_ * 16); \
    } } while (0)

    // prologue: two stages in flight (kt=0 into buf0, kt=1 into buf1)
    STAGE_KV(0, 0);
    STAGE_KV(1, 1);

    const int rsw = lr & 7;

    for (int kt = 0; kt < 16; ++kt) {
        const int cur = kt % 3;
        if (kt < 14) {
            STAGE_KV((kt + 2) % 3, kt + 2);
            __builtin_amdgcn_sched_barrier(0);
            vmcnt_asm<8>();   // kt's 4 loads done; kt+1,kt+2 (8) stay in flight
        } else if (kt == 14) {
            __builtin_amdgcn_sched_barrier(0);
            vmcnt_asm<4>();
        } else {
            __builtin_amdgcn_sched_barrier(0);
            vmcnt_asm<0>();
        }
        SBAR();

        f32x4 s[2][4];
        __builtin_amdgcn_s_setprio(1);
#pragma unroll
        for (int kf = 0; kf < 4; ++kf) {
            bf16x8 k0 = *reinterpret_cast<const bf16x8*>(
                &Ks[cur][(kf * 16 + lr) * 64 + ((lg ^ rsw) * 8)]);
            bf16x8 k1 = *reinterpret_cast<const bf16x8*>(
                &Ks[cur][(kf * 16 + lr) * 64 + (((4 + lg) ^ rsw) * 8)]);
#pragma unroll
            for (int q = 0; q < 2; ++q) {
                f32x4 a = __builtin_amdgcn_mfma_f32_16x16x32_bf16(
                    k0, qf[q][0], (f32x4){0.f, 0.f, 0.f, 0.f}, 0, 0, 0);
                s[q][kf] = __builtin_amdgcn_mfma_f32_16x16x32_bf16(k1, qf[q][1], a, 0, 0, 0);
            }
        }
        __builtin_amdgcn_s_setprio(0);

        union { u32 wd[4]; bf16x8 v; } pk[2][2];
#pragma unroll
        for (int q = 0; q < 2; ++q) {
#pragma unroll
            for (int kf = 0; kf < 4; ++kf)
#pragma unroll
                for (int r = 0; r < 4; ++r) s[q][kf][r] = __builtin_amdgcn_exp2f(s[q][kf][r]);
            float t0 = (s[q][0][0] + s[q][0][1]) + (s[q][0][2] + s[q][0][3]);
            float t1 = (s[q][1][0] + s[q][1][1]) + (s[q][1][2] + s[q][1][3]);
            float t2 = (s[q][2][0] + s[q][2][1]) + (s[q][2][2] + s[q][2][3]);
            float t3 = (s[q][3][0] + s[q][3][1]) + (s[q][3][2] + s[q][3][3]);
            lsum[q] += (t0 + t1) + (t2 + t3);
#pragma unroll
            for (int ks = 0; ks < 2; ++ks) {
                pk[q][ks].wd[0] = cvt_pk_bf16(s[q][2 * ks][0], s[q][2 * ks][1]);
                pk[q][ks].wd[1] = cvt_pk_bf16(s[q][2 * ks][2], s[q][2 * ks][3]);
                pk[q][ks].wd[2] = cvt_pk_bf16(s[q][2 * ks + 1][0], s[q][2 * ks + 1][1]);
                pk[q][ks].wd[3] = cvt_pk_bf16(s[q][2 * ks + 1][2], s[q][2 * ks + 1][3]);
            }
        }

        __builtin_amdgcn_s_setprio(1);
#pragma unroll
        for (int ks = 0; ks < 2; ++ks) {
#pragma unroll
            for (int df = 0; df < 4; ++df) {
                bf16x8 vb = *reinterpret_cast<const bf16x8*>(
                    &Vs[cur][(df * 16 + lr) * 64 + (((ks * 4 + lg) ^ rsw) * 8)]);
                o[0][df] = __builtin_amdgcn_mfma_f32_16x16x32_bf16(vb, pk[0][ks].v, o[0][df], 0, 0, 0);
                o[1][df] = __builtin_amdgcn_mfma_f32_16x16x32_bf16(vb, pk[1][ks].v, o[1][df], 0, 0, 0);
            }
        }
        __builtin_amdgcn_s_setprio(0);
        SBAR();
    }
#undef STAGE_KV

#pragma unroll
    for (int q = 0; q < 2; ++q) {
        float l = lsum[q];
        l += __shfl_xor(l, 16);
        l += __shfl_xor(l, 32);
        const float linv = 1.0f / l;
        u16* orow = attn_out +
            (size_t)(b * 1024 + qt * 128 + w * 32 + q * 16 + lr) * 768 + h * 64 + lg * 4;
#pragma unroll
        for (int df = 0; df < 4; ++df) {
            uint2 st;
            st.x = cvt_pk_bf16(o[q][df][0] * linv, o[q][df][1] * linv);
            st.y = cvt_pk_bf16(o[q][df][2] * linv, o[q][df][3] * linv);
            *reinterpret_cast<uint2*>(orow + df * 16) = st;
        }
    }
}

extern "C" void kernel_launch(void* const* d_in, const int* in_sizes, int n_in,
                              void* d_out, int out_size, void* d_ws, size_t ws_size,
                              hipStream_t stream) {
    (void)in_sizes; (void)n_in; (void)out_size; (void)ws_size;
    const float* x     = (const float*)d_in[0];   // [8,1024,768]
    const float* pos   = (const float*)d_in[1];   // [1,1024,64]
    const float* W_qkv = (const float*)d_in[2];   // [768,2304]
    const float* W_out = (const float*)d_in[3];   // [768,768]
    const float* b_out = (const float*)d_in[4];   // [768]
    float* out = (float*)d_out;                   // [8,1024,768]

    // workspace layout (bytes); Wqkv_t padded to 2336 rows, Wout_t to 800 rows
    char* ws = (char*)d_ws;
    u16* xb     = (u16*)(ws);                       // 8192x768   bf16 (12582912)
    u16* Wqkv_t = (u16*)(ws + 12582912);            // 2336x768   bf16 (3588096)
    u16* Wout_t = (u16*)(ws + 16171008);            // 800x768    bf16 (1228800)
    u16* qkv    = (u16*)(ws + 17399808);            // 8192x2304  bf16 (37748736)
    u16* Vt     = (u16*)(ws + 55148544);            // 96x64x1024 bf16 (12582912)
    u16* attn_o = (u16*)(ws + 67731456);            // 8192x768   bf16 (12582912)

    prep_kernel<<<5376, 256, 0, stream>>>(x, xb, W_qkv, Wqkv_t, W_out, Wout_t);
    // qkv = xb @ Wqkv^T : tile 128x192, grid 768 = 3 blocks/CU (best measured)
    gemm1_kernel<768><<<768, 256, 0, stream>>>(xb, Wqkv_t, qkv);
    rot_vtrans_kernel<<<7680, 256, 0, stream>>>(qkv, pos, Vt);
    attn_kernel<<<768, 256, 0, stream>>>(qkv, Vt, attn_o);
    // out = attn_o @ Wout^T + b : tile 256x96, grid exactly 256
    gemm_bigtile_kernel<8, 3, 128, 768, false><<<256, 512, 0, stream>>>(attn_o, Wout_t, out, b_out);
}